// Round 17
// baseline (5812.239 us; speedup 1.0000x reference)
//
#include <hip/hip_runtime.h>

// ---------------------------------------------------------------------------
// Recurrent ReLU net on MI355X — fused gate+payload, per-wave sub-flags, v17.
//   = r16 (1.985 ms) + ONE structural change on the publish side:
//   each of the 4 epilogue waves drains its OWN h stores (s_waitcnt vmcnt(0)
//   is per-wave) and immediately publishes its own u16 sub-flag; a cg's flag
//   is a u64 of 4 sub-flags. This deletes the 2nd __syncthreads and the
//   max-over-epilogue-waves slack from the serial publish chain; waves 4-7
//   begin polling step s+1 while the epilogue still runs.
//   Gate: 8 producer cgs x 8 B = 64 B; lane l loads the 16-B word (l&3)
//   (covers 2 cgs = 8 sub-flags), checks all u16 in {step, step+1}, __all
//   combines across lanes -> same single-round RTT as r16.
//   Ordering proofs re-verified with ONE barrier/step:
//     - sp half reuse: a wave writes sph[s&1] again at s+2, which requires
//       passing barrier B_{s+1}; epilogue waves reach B_{s+1} only after
//       their step-s sph reads (program order). Safe.
//     - ring WAR: gate(s) passed => all plane cgs' sub-flags >= s => every
//       plane WG passed B_{s-1} => all its waves consumed h_{s-1} => nobody
//       still reads h_{s-2} = the slot we overwrite with h_{s+1}. Safe.
//   Everything else identical to r16 (RING=3 sign-parity backstop, fused
//   speculative payload, W hi in LDS / lo in VGPRs, inline injection).
// ---------------------------------------------------------------------------

#define N_DIM   2048
#define B_DIM   64
#define T_DIM   128
#define NSENS   256
#define NOUT    128
#define NSTEP   512

#define NWG     256
#define THREADS 512
#define CW      32
#define RING    3
#define SLOT_F16 (B_DIM * N_DIM)       // 131072 f16 = 256 KB per slot
#define SP_S    20
#define SP_HALF (256 * SP_S)
#define LDS_W_F16 (CW * N_DIM)         // 128 KB hi
#define SMEM_MAIN (LDS_W_F16 * 2 + 2 * SP_HALF * 2)   // 151,552 B

typedef _Float16 f16x8 __attribute__((ext_vector_type(8)));
typedef _Float16 f16x4 __attribute__((ext_vector_type(4)));
typedef float    f32x4 __attribute__((ext_vector_type(4)));
typedef unsigned long long u64;
typedef unsigned short u16;

#define SIGN_M32 0x80008000u
#define SIGN_M64 0x8000800080008000ULL

union V16 { uint4 q; u64 u[2]; };

// ---------------- setup kernels ----------------

// slot 0 holds h_0 = -0 (sign SET, valid for even step 0).
// slot 1 first read at s=1 (expect CLEAR) -> init SET (invalid).
// slot 2 first read at s=2 (expect SET)  -> init CLEAR (invalid).
__global__ void k_init(uint4* __restrict__ ring, int* __restrict__ inv_sens,
                       int* __restrict__ inv_out, u64* __restrict__ flags) {
    const int i = blockIdx.x * blockDim.x + threadIdx.x;   // 49152 threads
    const int slot = i / (SLOT_F16 / 8);
    if (slot < RING) {
        const unsigned pat = (slot == 0 || (slot & 1)) ? SIGN_M32 : 0u;
        ring[i] = make_uint4(pat, pat, pat, pat);
    }
    if (i < N_DIM) { inv_sens[i] = -1; inv_out[i] = -1; }
    if (i < 256) flags[i] = 0ull;      // [4 planes][64 cg] u64 of 4 u16 sub-flags
}

__global__ void k_inv_scatter(int* inv_sens, int* inv_out,
                              const int* sidx, const int* oidx) {
    int i = threadIdx.x;
    if (i < NSENS) inv_sens[sidx[i]] = i;
    if (i < NOUT)  inv_out[oidx[i]] = i;
}

// ---------------- main persistent kernel ----------------
// slot layout: fp16 MFMA A-fragment order.
//   elem (b, j): f16 offset = ((b>>4)*64 + (j>>5))*512 + (((j>>3)&3)*16 + (b&15))*8 + (j&7)
// Fragment (pl, kt) = 1 KB, produced by WG (pl, cg=kt).
// Wave A-load: ONE dense dwordx4 sc1 per fragment (16 B/lane contiguous).

__global__ __launch_bounds__(THREADS, 2)
void rnn_main(const float* __restrict__ W_rec, const float* __restrict__ inputs,
              const float* __restrict__ W_in, const float* __restrict__ b_in,
              const int* __restrict__ inv_sens, const int* __restrict__ inv_out,
              _Float16* __restrict__ ring, _Float16* __restrict__ hc,
              u64* __restrict__ flags /* [4 planes][64 cg] u64 (4 u16 sub-flags) */)
{
    extern __shared__ _Float16 smem[];
    _Float16* w_hi = smem;                  // [128 blocks][512]  (kt_local*2+nt major)
    _Float16* sp   = smem + LDS_W_F16;      // [2][256][SP_S]

    const int tid   = threadIdx.x;
    const int wg    = blockIdx.x;
    const int pl    = wg & 3;        // plane: batch rows pl*16..+15
    const int cg    = wg >> 2;       // col group: cols cg*32..+31 (k-tile cg)
    const int jbase = cg * CW;

    const int lane = tid & 63;
    const int wv   = tid >> 6;       // wave = K-slab (k-tiles wv*8..wv*8+7)
    const int lrow = lane & 15;
    const int quad = lane >> 4;

    // ---- stage W: hi -> LDS, lo (x4096 residual) -> VGPRs ----
    f16x8 blo[8][2];
#pragma unroll
    for (int nt = 0; nt < 2; ++nt) {
        const float* wr = W_rec + (size_t)(jbase + nt * 16 + lrow) * N_DIM
                        + wv * 256 + quad * 8;
#pragma unroll
        for (int ks = 0; ks < 8; ++ks) {
            const float4 wa = ((const float4*)(wr + ks * 32))[0];
            const float4 wb = ((const float4*)(wr + ks * 32))[1];
            const float w8[8] = {wa.x, wa.y, wa.z, wa.w, wb.x, wb.y, wb.z, wb.w};
            f16x8 hi8;
#pragma unroll
            for (int e = 0; e < 8; ++e) {
                const _Float16 hi = (_Float16)w8[e];
                hi8[e] = hi;
                blo[ks][nt][e] = (_Float16)((w8[e] - (float)hi) * 4096.0f);
            }
            *(f16x8*)(w_hi + ((((wv * 8 + ks) * 2 + nt)) << 9) + lane * 8) = hi8;
        }
    }

    // ---- epilogue constants (threads 0..255): one (b, col-pair) each ----
    const int ep_bl = tid >> 4;            // local batch row 0..15
    const int ep_b  = pl * 16 + ep_bl;     // global batch row
    const int ep_jp = tid & 15;            // col pair index
    const int ej    = jbase + ep_jp * 2;   // global col, even
    int ep_sA = -1, ep_sB = -1, ep_uA = -1, ep_uB = -1, ep_off = 0;
    if (tid < 256) {
        ep_sA = inv_sens[ej];  ep_sB = inv_sens[ej + 1];
        ep_uA = inv_out[ej];   ep_uB = inv_out[ej + 1];
        ep_off = ((pl * 64 + cg) << 9)
               + ((((ej >> 3) & 3) * 16 + ep_bl) << 3) + (ej & 7);
    }
    __syncthreads();

    // gate base: 8 producer cg flag u64s (64 B); lane reads word (lane&3)
    const char* gwl = (const char*)(flags + pl * 64 + wv * 8) + (lane & 3) * 16;
    // publish target: sub-flag w of own cg (epilogue wave w = tid>>6 for tid<256)
    u16* myflag = (u16*)(flags + pl * 64 + cg) + (tid >> 6);

    int slot_r = 0, slot_w = 1;

    for (int step = 0; step < NSTEP; ++step) {
        const int t = step >> 2, micro = step & 3;
        const bool expSet = (step & 1) == 0;     // parity of h_step
        const _Float16* __restrict__ hcur = ring + (size_t)slot_r * SLOT_F16;
        _Float16* __restrict__       hnxt = ring + (size_t)slot_w * SLOT_F16;

        // ---- hi fragments from LDS (before the poll; overlaps with loads) ----
        f16x8 bh[8][2];
#pragma unroll
        for (int ks = 0; ks < 8; ++ks)
#pragma unroll
            for (int nt = 0; nt < 2; ++nt)
                bh[ks][nt] = *(const f16x8*)(w_hi + (((wv * 8 + ks) * 2 + nt) << 9) + lane * 8);

        // ---- fused gate + payload rounds ----
        const _Float16* hb = hcur + ((pl * 64 + wv * 8) << 9) + lane * 8;
        V16 a[8];
        {
            const u64 rep = 0x0001000100010001ULL * (unsigned)(u16)step;
            while (true) {
                V16 g;
                asm volatile(
                    "global_load_dwordx4 %0, %9, off sc1\n\t"
                    "global_load_dwordx4 %1, %10, off sc1\n\t"
                    "global_load_dwordx4 %2, %11, off sc1\n\t"
                    "global_load_dwordx4 %3, %12, off sc1\n\t"
                    "global_load_dwordx4 %4, %13, off sc1\n\t"
                    "global_load_dwordx4 %5, %14, off sc1\n\t"
                    "global_load_dwordx4 %6, %15, off sc1\n\t"
                    "global_load_dwordx4 %7, %16, off sc1\n\t"
                    "global_load_dwordx4 %8, %17, off sc1\n\t"
                    "s_waitcnt vmcnt(0)"
                    : "=v"(g.q),
                      "=v"(a[0].q), "=v"(a[1].q), "=v"(a[2].q), "=v"(a[3].q),
                      "=v"(a[4].q), "=v"(a[5].q), "=v"(a[6].q), "=v"(a[7].q)
                    : "v"(gwl),
                      "v"(hb),        "v"(hb + 512),  "v"(hb + 1024), "v"(hb + 1536),
                      "v"(hb + 2048), "v"(hb + 2560), "v"(hb + 3072), "v"(hb + 3584)
                    : "memory");
                const bool ok = (((g.u[0] - rep) | (g.u[1] - rep))
                                 & 0xFFFEFFFEFFFEFFFEULL) == 0ull;
                if (__all((int)ok)) break;
                __builtin_amdgcn_s_sleep(1);
            }
        }

        f32x4 acch[2], accl[2];
#pragma unroll
        for (int nt = 0; nt < 2; ++nt) {
            acch[nt] = (f32x4){0.f, 0.f, 0.f, 0.f};
            accl[nt] = (f32x4){0.f, 0.f, 0.f, 0.f};
        }

        // ---- parity backstop (validates pre-loaded payload; rare reloads) ----
        unsigned live = 0xFFu;
        while (live) {
#pragma unroll
            for (int f = 0; f < 8; ++f) if (live & (1u << f)) {
                const u64 band = a[f].u[0] & a[f].u[1];
                const u64 bor  = a[f].u[0] | a[f].u[1];
                const bool ok = expSet ? ((band & SIGN_M64) == SIGN_M64)
                                       : ((bor  & SIGN_M64) == 0);
                if (__all((int)ok)) {
                    union { u64 u[2]; f16x8 v; } c;
                    c.u[0] = expSet ? (a[f].u[0] ^ SIGN_M64) : a[f].u[0];
                    c.u[1] = expSet ? (a[f].u[1] ^ SIGN_M64) : a[f].u[1];
                    const f16x8 Af = c.v;
                    acch[0] = __builtin_amdgcn_mfma_f32_16x16x32_f16(Af, bh[f][0], acch[0], 0, 0, 0);
                    accl[0] = __builtin_amdgcn_mfma_f32_16x16x32_f16(Af, blo[f][0], accl[0], 0, 0, 0);
                    acch[1] = __builtin_amdgcn_mfma_f32_16x16x32_f16(Af, bh[f][1], acch[1], 0, 0, 0);
                    accl[1] = __builtin_amdgcn_mfma_f32_16x16x32_f16(Af, blo[f][1], accl[1], 0, 0, 0);
                    live &= ~(1u << f);
                }
            }
            if (live) {
                __builtin_amdgcn_s_sleep(1);
#pragma unroll
                for (int f = 0; f < 8; ++f) if (live & (1u << f))
                    asm volatile("global_load_dwordx4 %0, %1, off sc1\n\t"
                                 "s_waitcnt vmcnt(0)"
                                 : "=v"(a[f].q) : "v"(hb + f * 512) : "memory");
            }
        }

        // ---- K-slab partial (hi + lo/4096) to LDS scratch ----
        _Float16* sph = sp + (step & 1) * SP_HALF;
#pragma unroll
        for (int nt = 0; nt < 2; ++nt) {
            f16x4 pv;
#pragma unroll
            for (int r = 0; r < 4; ++r)
                pv[r] = (_Float16)(acch[nt][r] + accl[nt][r] * 2.44140625e-4f);
            *(f16x4*)(sph + (wv * 32 + nt * 16 + lrow) * SP_S + quad * 4) = pv;
        }
        __syncthreads();   // all waves consumed h_step (the ONLY barrier/step)

        // ---- epilogue: waves 0..3, one (b, col-pair) per thread; each wave
        // drains its own stores and publishes its own sub-flag immediately ----
        if (tid < 256) {
            float vA = 0.f, vB = 0.f;
#pragma unroll
            for (int s8 = 0; s8 < 8; ++s8) {
                vA += (float)sph[(s8 * 32 + ep_jp * 2    ) * SP_S + ep_bl];
                vB += (float)sph[(s8 * 32 + ep_jp * 2 + 1) * SP_S + ep_bl];
            }
            if (micro == 0 && (ep_sA >= 0 || ep_sB >= 0)) {
                const float4 x = *(const float4*)(inputs + ((ep_b * T_DIM + t) << 2));
                if (ep_sA >= 0) {
                    const float4 w = *(const float4*)(W_in + (ep_sA << 2));
                    vA += b_in[ep_sA] + x.x * w.x + x.y * w.y + x.z * w.z + x.w * w.w;
                }
                if (ep_sB >= 0) {
                    const float4 w = *(const float4*)(W_in + (ep_sB << 2));
                    vB += b_in[ep_sB] + x.x * w.x + x.y * w.y + x.z * w.z + x.w * w.w;
                }
            }
            union { _Float16 h[2]; unsigned u; } pk;
            pk.h[0] = (_Float16)fmaxf(vA, 0.0f);
            pk.h[1] = (_Float16)fmaxf(vB, 0.0f);
            if (micro == 3) {
                if (ep_uA >= 0) hc[(t * NOUT + ep_uA) * B_DIM + ep_b] = pk.h[0];
                if (ep_uB >= 0) hc[(t * NOUT + ep_uB) * B_DIM + ep_b] = pk.h[1];
            }
            // parity of h_{step+1}: step+1 even -> sign SET (h>=0, OR sets)
            pk.u |= (step & 1) ? SIGN_M32 : 0u;
            __hip_atomic_store((unsigned*)(hnxt + ep_off), pk.u,
                               __ATOMIC_RELAXED, __HIP_MEMORY_SCOPE_AGENT);
            // drain THIS wave's stores, then publish this wave's sub-flag
            asm volatile("s_waitcnt vmcnt(0)" ::: "memory");
            if ((tid & 63) == 0)
                __hip_atomic_store(myflag, (u16)(step + 1),
                                   __ATOMIC_RELAXED, __HIP_MEMORY_SCOPE_AGENT);
        }

        slot_r = (slot_r + 1 == RING) ? 0 : slot_r + 1;
        slot_w = (slot_w + 1 == RING) ? 0 : slot_w + 1;
    }
}

// ---------------- final readout: out[b][t][o] = hc[t][:][b] . W_out[o][:] + b_out ----

__global__ __launch_bounds__(128)
void k_readout(float* __restrict__ out, const _Float16* __restrict__ hc,
               const float* __restrict__ W_out, const float* __restrict__ b_out) {
    __shared__ _Float16 sh[NOUT * B_DIM];
    const int t = blockIdx.x, tid = threadIdx.x;
    const unsigned int* src = (const unsigned int*)(hc + (size_t)t * NOUT * B_DIM);
    for (int i = tid; i < NOUT * B_DIM / 2; i += 128)
        ((unsigned int*)sh)[i] = src[i];
    __syncthreads();
    const int o = tid >> 6, b = tid & 63;
    float acc = b_out[o];
#pragma unroll 8
    for (int u = 0; u < NOUT; ++u)
        acc += (float)sh[u * B_DIM + b] * W_out[o * NOUT + u];
    out[(b * T_DIM + t) * 2 + o] = acc;
}

// ---------------- host launch ----------------

extern "C" void kernel_launch(void* const* d_in, const int* in_sizes, int n_in,
                              void* d_out, int out_size, void* d_ws, size_t ws_size,
                              hipStream_t stream) {
    const float* inputs = (const float*)d_in[0];
    const float* W_rec  = (const float*)d_in[1];
    const float* W_in   = (const float*)d_in[2];
    const float* b_in   = (const float*)d_in[3];
    const float* W_out  = (const float*)d_in[4];
    const float* b_out  = (const float*)d_in[5];
    const int*   sidx   = (const int*)d_in[6];
    const int*   oidx   = (const int*)d_in[7];

    // ws: ring 786,432 + hc 2,097,152 + inv 16,384 + flags 2,048 = 2,902,016 B
    char* ws = (char*)d_ws;
    _Float16* ring     = (_Float16*)ws;
    _Float16* hc       = (_Float16*)(ws + 786432);
    int*      inv_sens = (int*)(ws + 786432 + 2097152);
    int*      inv_out  = inv_sens + N_DIM;
    u64*      flags    = (u64*)(inv_out + N_DIM);

    // ring fill: 3*131072/8 = 49,152 uint4 -> 192 blocks x 256
    k_init<<<192, 256, 0, stream>>>((uint4*)ring, inv_sens, inv_out, flags);
    k_inv_scatter<<<1, 256, 0, stream>>>(inv_sens, inv_out, sidx, oidx);

    (void)hipFuncSetAttribute((const void*)rnn_main,
                              hipFuncAttributeMaxDynamicSharedMemorySize, SMEM_MAIN);

    rnn_main<<<NWG, THREADS, SMEM_MAIN, stream>>>(
        W_rec, inputs, W_in, b_in, inv_sens, inv_out, ring, hc, flags);

    k_readout<<<T_DIM, 128, 0, stream>>>((float*)d_out, hc, W_out, b_out);
}

// Round 18
// 1970.773 us; speedup vs baseline: 2.9492x; 2.9492x over previous
//
#include <hip/hip_runtime.h>

// ---------------------------------------------------------------------------
// Recurrent ReLU net on MI355X — fused gate+payload dataflow, RING=3, v18.
//   EXACT REVERT to r16 (1.985 ms — best verified). r17's per-wave sub-flag
//   publish regressed 2.9x: gate latency became max over 4 independent wave
//   drains+stores (serialized on one MALL word), while fused speculative
//   polling amplified fabric traffic during the longer waits (FETCH +80 MB).
//   Lesson: speculative polling requires a SHORT, SINGLE publish event.
//   Design (verified over r12/r15/r16):
//     - 256 persistent WGs: plane = wg&3 (16 batch rows), cg = wg>>2 (32 cols)
//     - h ring: 3 slots, fp16 MFMA-A-fragment layout, sc1 (MALL) traffic
//     - per (plane, k-slab) 16-B word of 8 u16 producer counters (no RMW);
//       consumer poll fused with all 8 payload dwordx4 loads (one asm block,
//       one joint drain) -> flag observation round already carries payload
//     - sign-parity backstop (even steps store -h): catches flag-beats-data
//       and tearing; RING=3 (odd) flips parity on slot reuse -> stale never
//       validates. WAR safe via transitive skew<=1 argument.
//     - W: hi fp16 in LDS (128 KB), lo (x4096 residual) in VGPRs; injection
//       computed inline in the epilogue.
// ---------------------------------------------------------------------------

#define N_DIM   2048
#define B_DIM   64
#define T_DIM   128
#define NSENS   256
#define NOUT    128
#define NSTEP   512

#define NWG     256
#define THREADS 512
#define CW      32
#define RING    3
#define SLOT_F16 (B_DIM * N_DIM)       // 131072 f16 = 256 KB per slot
#define SP_S    20
#define SP_HALF (256 * SP_S)
#define LDS_W_F16 (CW * N_DIM)         // 128 KB hi
#define SMEM_MAIN (LDS_W_F16 * 2 + 2 * SP_HALF * 2)   // 151,552 B

typedef _Float16 f16x8 __attribute__((ext_vector_type(8)));
typedef _Float16 f16x4 __attribute__((ext_vector_type(4)));
typedef float    f32x4 __attribute__((ext_vector_type(4)));
typedef unsigned long long u64;
typedef unsigned short u16;

#define SIGN_M32 0x80008000u
#define SIGN_M64 0x8000800080008000ULL

union V16 { uint4 q; u64 u[2]; };

// ---------------- setup kernels ----------------

// slot 0 holds h_0 = -0 (sign SET, valid for even step 0).
// slot 1 first read at s=1 (expect CLEAR) -> init SET (invalid).
// slot 2 first read at s=2 (expect SET)  -> init CLEAR (invalid).
__global__ void k_init(uint4* __restrict__ ring, int* __restrict__ inv_sens,
                       int* __restrict__ inv_out, u64* __restrict__ flags) {
    const int i = blockIdx.x * blockDim.x + threadIdx.x;   // 49152 threads
    const int slot = i / (SLOT_F16 / 8);
    if (slot < RING) {
        const unsigned pat = (slot == 0 || (slot & 1)) ? SIGN_M32 : 0u;
        ring[i] = make_uint4(pat, pat, pat, pat);
    }
    if (i < N_DIM) { inv_sens[i] = -1; inv_out[i] = -1; }
    if (i < 64) flags[i] = 0ull;       // 4 planes x 8 words of 8 u16 counters
}

__global__ void k_inv_scatter(int* inv_sens, int* inv_out,
                              const int* sidx, const int* oidx) {
    int i = threadIdx.x;
    if (i < NSENS) inv_sens[sidx[i]] = i;
    if (i < NOUT)  inv_out[oidx[i]] = i;
}

// ---------------- main persistent kernel ----------------
// slot layout: fp16 MFMA A-fragment order.
//   elem (b, j): f16 offset = ((b>>4)*64 + (j>>5))*512 + (((j>>3)&3)*16 + (b&15))*8 + (j&7)
// Fragment (pl, kt) = 1 KB, produced by WG (pl, cg=kt).
// Wave A-load: ONE dense dwordx4 sc1 per fragment (16 B/lane contiguous).

__global__ __launch_bounds__(THREADS, 2)
void rnn_main(const float* __restrict__ W_rec, const float* __restrict__ inputs,
              const float* __restrict__ W_in, const float* __restrict__ b_in,
              const int* __restrict__ inv_sens, const int* __restrict__ inv_out,
              _Float16* __restrict__ ring, _Float16* __restrict__ hc,
              u16* __restrict__ flags /* [4 planes][64 cg] u16 */)
{
    extern __shared__ _Float16 smem[];
    _Float16* w_hi = smem;                  // [128 blocks][512]  (kt_local*2+nt major)
    _Float16* sp   = smem + LDS_W_F16;      // [2][256][SP_S]

    const int tid   = threadIdx.x;
    const int wg    = blockIdx.x;
    const int pl    = wg & 3;        // plane: batch rows pl*16..+15
    const int cg    = wg >> 2;       // col group: cols cg*32..+31 (k-tile cg)
    const int jbase = cg * CW;

    const int lane = tid & 63;
    const int wv   = tid >> 6;       // wave = K-slab (k-tiles wv*8..wv*8+7)
    const int lrow = lane & 15;
    const int quad = lane >> 4;

    // ---- stage W: hi -> LDS, lo (x4096 residual) -> VGPRs ----
    f16x8 blo[8][2];
#pragma unroll
    for (int nt = 0; nt < 2; ++nt) {
        const float* wr = W_rec + (size_t)(jbase + nt * 16 + lrow) * N_DIM
                        + wv * 256 + quad * 8;
#pragma unroll
        for (int ks = 0; ks < 8; ++ks) {
            const float4 wa = ((const float4*)(wr + ks * 32))[0];
            const float4 wb = ((const float4*)(wr + ks * 32))[1];
            const float w8[8] = {wa.x, wa.y, wa.z, wa.w, wb.x, wb.y, wb.z, wb.w};
            f16x8 hi8;
#pragma unroll
            for (int e = 0; e < 8; ++e) {
                const _Float16 hi = (_Float16)w8[e];
                hi8[e] = hi;
                blo[ks][nt][e] = (_Float16)((w8[e] - (float)hi) * 4096.0f);
            }
            *(f16x8*)(w_hi + ((((wv * 8 + ks) * 2 + nt)) << 9) + lane * 8) = hi8;
        }
    }

    // ---- epilogue constants (threads 0..255): one (b, col-pair) each ----
    const int ep_bl = tid >> 4;            // local batch row 0..15
    const int ep_b  = pl * 16 + ep_bl;     // global batch row
    const int ep_jp = tid & 15;            // col pair index
    const int ej    = jbase + ep_jp * 2;   // global col, even
    int ep_sA = -1, ep_sB = -1, ep_uA = -1, ep_uB = -1, ep_off = 0;
    if (tid < 256) {
        ep_sA = inv_sens[ej];  ep_sB = inv_sens[ej + 1];
        ep_uA = inv_out[ej];   ep_uB = inv_out[ej + 1];
        ep_off = ((pl * 64 + cg) << 9)
               + ((((ej >> 3) & 3) * 16 + ep_bl) << 3) + (ej & 7);
    }
    __syncthreads();

    // combined gate word: 8 u16 counters for producer cgs wv*8..wv*8+7
    const u64* gw = (const u64*)(flags + pl * 64 + wv * 8);   // 16-B aligned

    int slot_r = 0, slot_w = 1;

    for (int step = 0; step < NSTEP; ++step) {
        const int t = step >> 2, micro = step & 3;
        const bool expSet = (step & 1) == 0;     // parity of h_step
        const _Float16* __restrict__ hcur = ring + (size_t)slot_r * SLOT_F16;
        _Float16* __restrict__       hnxt = ring + (size_t)slot_w * SLOT_F16;

        // ---- hi fragments from LDS (before the poll; overlaps with loads) ----
        f16x8 bh[8][2];
#pragma unroll
        for (int ks = 0; ks < 8; ++ks)
#pragma unroll
            for (int nt = 0; nt < 2; ++nt)
                bh[ks][nt] = *(const f16x8*)(w_hi + (((wv * 8 + ks) * 2 + nt) << 9) + lane * 8);

        // ---- fused gate + payload rounds: each poll issues the gate word AND
        // all 8 payload fragments; the round that sees the flag already holds
        // the (normally fresh) payload -> no serial payload RTT. ----
        const _Float16* hb = hcur + ((pl * 64 + wv * 8) << 9) + lane * 8;
        V16 a[8];
        {
            const u64 rep = 0x0001000100010001ULL * (unsigned)(u16)step;
            while (true) {
                V16 g;
                asm volatile(
                    "global_load_dwordx4 %0, %9, off sc1\n\t"
                    "global_load_dwordx4 %1, %10, off sc1\n\t"
                    "global_load_dwordx4 %2, %11, off sc1\n\t"
                    "global_load_dwordx4 %3, %12, off sc1\n\t"
                    "global_load_dwordx4 %4, %13, off sc1\n\t"
                    "global_load_dwordx4 %5, %14, off sc1\n\t"
                    "global_load_dwordx4 %6, %15, off sc1\n\t"
                    "global_load_dwordx4 %7, %16, off sc1\n\t"
                    "global_load_dwordx4 %8, %17, off sc1\n\t"
                    "s_waitcnt vmcnt(0)"
                    : "=v"(g.q),
                      "=v"(a[0].q), "=v"(a[1].q), "=v"(a[2].q), "=v"(a[3].q),
                      "=v"(a[4].q), "=v"(a[5].q), "=v"(a[6].q), "=v"(a[7].q)
                    : "v"(gw),
                      "v"(hb),        "v"(hb + 512),  "v"(hb + 1024), "v"(hb + 1536),
                      "v"(hb + 2048), "v"(hb + 2560), "v"(hb + 3072), "v"(hb + 3584)
                    : "memory");
                if ((((g.u[0] - rep) | (g.u[1] - rep)) & 0xFFFEFFFEFFFEFFFEULL) == 0ull)
                    break;
                __builtin_amdgcn_s_sleep(1);
            }
        }

        f32x4 acch[2], accl[2];
#pragma unroll
        for (int nt = 0; nt < 2; ++nt) {
            acch[nt] = (f32x4){0.f, 0.f, 0.f, 0.f};
            accl[nt] = (f32x4){0.f, 0.f, 0.f, 0.f};
        }

        // ---- parity backstop (validates pre-loaded payload; rare reloads) ----
        unsigned live = 0xFFu;
        while (live) {
#pragma unroll
            for (int f = 0; f < 8; ++f) if (live & (1u << f)) {
                const u64 band = a[f].u[0] & a[f].u[1];
                const u64 bor  = a[f].u[0] | a[f].u[1];
                const bool ok = expSet ? ((band & SIGN_M64) == SIGN_M64)
                                       : ((bor  & SIGN_M64) == 0);
                if (__all((int)ok)) {
                    union { u64 u[2]; f16x8 v; } c;
                    c.u[0] = expSet ? (a[f].u[0] ^ SIGN_M64) : a[f].u[0];
                    c.u[1] = expSet ? (a[f].u[1] ^ SIGN_M64) : a[f].u[1];
                    const f16x8 Af = c.v;
                    acch[0] = __builtin_amdgcn_mfma_f32_16x16x32_f16(Af, bh[f][0], acch[0], 0, 0, 0);
                    accl[0] = __builtin_amdgcn_mfma_f32_16x16x32_f16(Af, blo[f][0], accl[0], 0, 0, 0);
                    acch[1] = __builtin_amdgcn_mfma_f32_16x16x32_f16(Af, bh[f][1], acch[1], 0, 0, 0);
                    accl[1] = __builtin_amdgcn_mfma_f32_16x16x32_f16(Af, blo[f][1], accl[1], 0, 0, 0);
                    live &= ~(1u << f);
                }
            }
            if (live) {
                __builtin_amdgcn_s_sleep(1);
#pragma unroll
                for (int f = 0; f < 8; ++f) if (live & (1u << f))
                    asm volatile("global_load_dwordx4 %0, %1, off sc1\n\t"
                                 "s_waitcnt vmcnt(0)"
                                 : "=v"(a[f].q) : "v"(hb + f * 512) : "memory");
            }
        }

        // ---- K-slab partial (hi + lo/4096) to LDS scratch ----
        _Float16* sph = sp + (step & 1) * SP_HALF;
#pragma unroll
        for (int nt = 0; nt < 2; ++nt) {
            f16x4 pv;
#pragma unroll
            for (int r = 0; r < 4; ++r)
                pv[r] = (_Float16)(acch[nt][r] + accl[nt][r] * 2.44140625e-4f);
            *(f16x4*)(sph + (wv * 32 + nt * 16 + lrow) * SP_S + quad * 4) = pv;
        }
        __syncthreads();   // all waves consumed h_step

        // ---- epilogue: 256 threads, one (b, col-pair) each ----
        if (tid < 256) {
            float vA = 0.f, vB = 0.f;
#pragma unroll
            for (int s8 = 0; s8 < 8; ++s8) {
                vA += (float)sph[(s8 * 32 + ep_jp * 2    ) * SP_S + ep_bl];
                vB += (float)sph[(s8 * 32 + ep_jp * 2 + 1) * SP_S + ep_bl];
            }
            if (micro == 0 && (ep_sA >= 0 || ep_sB >= 0)) {
                const float4 x = *(const float4*)(inputs + ((ep_b * T_DIM + t) << 2));
                if (ep_sA >= 0) {
                    const float4 w = *(const float4*)(W_in + (ep_sA << 2));
                    vA += b_in[ep_sA] + x.x * w.x + x.y * w.y + x.z * w.z + x.w * w.w;
                }
                if (ep_sB >= 0) {
                    const float4 w = *(const float4*)(W_in + (ep_sB << 2));
                    vB += b_in[ep_sB] + x.x * w.x + x.y * w.y + x.z * w.z + x.w * w.w;
                }
            }
            union { _Float16 h[2]; unsigned u; } pk;
            pk.h[0] = (_Float16)fmaxf(vA, 0.0f);
            pk.h[1] = (_Float16)fmaxf(vB, 0.0f);
            if (micro == 3) {
                if (ep_uA >= 0) hc[(t * NOUT + ep_uA) * B_DIM + ep_b] = pk.h[0];
                if (ep_uB >= 0) hc[(t * NOUT + ep_uB) * B_DIM + ep_b] = pk.h[1];
            }
            // parity of h_{step+1}: step+1 even -> sign SET (h>=0, OR sets)
            pk.u |= (step & 1) ? SIGN_M32 : 0u;
            __hip_atomic_store((unsigned*)(hnxt + ep_off), pk.u,
                               __ATOMIC_RELAXED, __HIP_MEMORY_SCOPE_AGENT);
        }
        __syncthreads();   // drain all waves' stores, then publish
        if (tid == 0)
            __hip_atomic_store(flags + pl * 64 + cg, (u16)(step + 1),
                               __ATOMIC_RELAXED, __HIP_MEMORY_SCOPE_AGENT);

        slot_r = (slot_r + 1 == RING) ? 0 : slot_r + 1;
        slot_w = (slot_w + 1 == RING) ? 0 : slot_w + 1;
    }
}

// ---------------- final readout: out[b][t][o] = hc[t][:][b] . W_out[o][:] + b_out ----

__global__ __launch_bounds__(128)
void k_readout(float* __restrict__ out, const _Float16* __restrict__ hc,
               const float* __restrict__ W_out, const float* __restrict__ b_out) {
    __shared__ _Float16 sh[NOUT * B_DIM];
    const int t = blockIdx.x, tid = threadIdx.x;
    const unsigned int* src = (const unsigned int*)(hc + (size_t)t * NOUT * B_DIM);
    for (int i = tid; i < NOUT * B_DIM / 2; i += 128)
        ((unsigned int*)sh)[i] = src[i];
    __syncthreads();
    const int o = tid >> 6, b = tid & 63;
    float acc = b_out[o];
#pragma unroll 8
    for (int u = 0; u < NOUT; ++u)
        acc += (float)sh[u * B_DIM + b] * W_out[o * NOUT + u];
    out[(b * T_DIM + t) * 2 + o] = acc;
}

// ---------------- host launch ----------------

extern "C" void kernel_launch(void* const* d_in, const int* in_sizes, int n_in,
                              void* d_out, int out_size, void* d_ws, size_t ws_size,
                              hipStream_t stream) {
    const float* inputs = (const float*)d_in[0];
    const float* W_rec  = (const float*)d_in[1];
    const float* W_in   = (const float*)d_in[2];
    const float* b_in   = (const float*)d_in[3];
    const float* W_out  = (const float*)d_in[4];
    const float* b_out  = (const float*)d_in[5];
    const int*   sidx   = (const int*)d_in[6];
    const int*   oidx   = (const int*)d_in[7];

    // ws: ring 786,432 + hc 2,097,152 + inv 16,384 + flags 512 = 2,900,480 B
    char* ws = (char*)d_ws;
    _Float16* ring     = (_Float16*)ws;
    _Float16* hc       = (_Float16*)(ws + 786432);
    int*      inv_sens = (int*)(ws + 786432 + 2097152);
    int*      inv_out  = inv_sens + N_DIM;
    u16*      flags    = (u16*)(inv_out + N_DIM);

    // ring fill: 3*131072/8 = 49,152 uint4 -> 192 blocks x 256
    k_init<<<192, 256, 0, stream>>>((uint4*)ring, inv_sens, inv_out, (u64*)flags);
    k_inv_scatter<<<1, 256, 0, stream>>>(inv_sens, inv_out, sidx, oidx);

    (void)hipFuncSetAttribute((const void*)rnn_main,
                              hipFuncAttributeMaxDynamicSharedMemorySize, SMEM_MAIN);

    rnn_main<<<NWG, THREADS, SMEM_MAIN, stream>>>(
        W_rec, inputs, W_in, b_in, inv_sens, inv_out, ring, hc, flags);

    k_readout<<<T_DIM, 128, 0, stream>>>((float*)d_out, hc, W_out, b_out);
}